// Round 16
// baseline (55.877 us; speedup 1.0000x reference)
//
#include <hip/hip_runtime.h>
#include <hip/hip_bf16.h>
#include <math.h>

// Problem constants
#define B_    16
#define C_    256
#define L_    64
#define N_    8192
#define HEAD_ 8
#define HC_   32        // C/HEAD
#define M_    12

#define SQRT32F 5.656854249492380f
#define PI_F    3.14159265358979323846f
#define BN_INV  0.99999500003749969f     // 1/sqrt(1+1e-5)

typedef float v4f __attribute__((ext_vector_type(4)));

// ---------------------------------------------------------------------------
// Kernel 1: encoder attention per (b,h,half). 256 blocks x 512 threads.
// Each block: full k,v GEMM (64 rows), q GEMM for its 32 query cols,
// 32x64 scores, softmax, PV + Fourier + residual -> enc (global).
// Full CU coverage; per-CU GEMM work 0.83x of R14.
// ---------------------------------------------------------------------------
__global__ __launch_bounds__(512) void enc_half(
    const float* __restrict__ xt, const float* __restrict__ enc_w,
    const float* __restrict__ enc_b, const float* __restrict__ weights,
    float* __restrict__ enc)
{
    __shared__ float Xs[C_][L_];          // 64 KB  xt[b] as [c][l]
    __shared__ float qkv_s[96][68];       // 26 KB  rows 0..31 q, 32..63 k, 64..95 v
    __shared__ float P[32][68];           // 8.7 KB scores for this l-half
    __shared__ float wts[HC_][24];        // 3 KB
    const int t    = threadIdx.x;         // 0..511
    const int b    = blockIdx.x >> 4;
    const int h    = (blockIdx.x >> 1) & 7;
    const int half = blockIdx.x & 1;
    const float* xtb = xt + (size_t)b * (C_ * L_);

    // ---- stage xt[b] + weights h-slice ----
    #pragma unroll
    for (int i = 0; i < 8; ++i) {
        int q = t + i * 512;
        int c = q >> 4, l4 = (q & 15) * 4;
        *reinterpret_cast<float4*>(&Xs[c][l4]) =
            *reinterpret_cast<const float4*>(&xtb[q * 4]);
    }
    #pragma unroll
    for (int idx = t; idx < HC_ * 24; idx += 512)
        wts[idx / 24][idx % 24] = weights[(h * HC_) * 24 + idx];
    __syncthreads();

    // ---- qkv GEMM ----
    // all threads: k-row (t>>4), v-row (t>>4), col quad (t&15)*4   (full 64 cols)
    // threads <256 (waves 0-3): q-row (t>>3), col quad half*32+(t&7)*4
    {
        const int kvr  = t >> 4;              // 0..31
        const int kvc4 = (t & 15) * 4;
        const int qr   = t >> 3;              // 0..31 (t<256)
        const int qc4  = half * 32 + (t & 7) * 4;
        const float* wk = enc_w + (size_t)(C_ + h * HC_ + kvr) * C_;
        const float* wv = enc_w + (size_t)(2 * C_ + h * HC_ + kvr) * C_;
        const float* wq = enc_w + (size_t)(h * HC_ + (qr & 31)) * C_;
        float4 acck = {}, accv = {}, accq = {};
        #pragma unroll 2
        for (int c0 = 0; c0 < C_; c0 += 4) {
            float4 xk0 = *reinterpret_cast<const float4*>(&Xs[c0 + 0][kvc4]);
            float4 xk1 = *reinterpret_cast<const float4*>(&Xs[c0 + 1][kvc4]);
            float4 xk2 = *reinterpret_cast<const float4*>(&Xs[c0 + 2][kvc4]);
            float4 xk3 = *reinterpret_cast<const float4*>(&Xs[c0 + 3][kvc4]);
            float4 wk4 = *reinterpret_cast<const float4*>(&wk[c0]);
            float4 wv4 = *reinterpret_cast<const float4*>(&wv[c0]);
            acck.x += wk4.x * xk0.x + wk4.y * xk1.x + wk4.z * xk2.x + wk4.w * xk3.x;
            acck.y += wk4.x * xk0.y + wk4.y * xk1.y + wk4.z * xk2.y + wk4.w * xk3.y;
            acck.z += wk4.x * xk0.z + wk4.y * xk1.z + wk4.z * xk2.z + wk4.w * xk3.z;
            acck.w += wk4.x * xk0.w + wk4.y * xk1.w + wk4.z * xk2.w + wk4.w * xk3.w;
            accv.x += wv4.x * xk0.x + wv4.y * xk1.x + wv4.z * xk2.x + wv4.w * xk3.x;
            accv.y += wv4.x * xk0.y + wv4.y * xk1.y + wv4.z * xk2.y + wv4.w * xk3.y;
            accv.z += wv4.x * xk0.z + wv4.y * xk1.z + wv4.z * xk2.z + wv4.w * xk3.z;
            accv.w += wv4.x * xk0.w + wv4.y * xk1.w + wv4.z * xk2.w + wv4.w * xk3.w;
            if (t < 256) {
                float4 xq0 = *reinterpret_cast<const float4*>(&Xs[c0 + 0][qc4]);
                float4 xq1 = *reinterpret_cast<const float4*>(&Xs[c0 + 1][qc4]);
                float4 xq2 = *reinterpret_cast<const float4*>(&Xs[c0 + 2][qc4]);
                float4 xq3 = *reinterpret_cast<const float4*>(&Xs[c0 + 3][qc4]);
                float4 wq4 = *reinterpret_cast<const float4*>(&wq[c0]);
                accq.x += wq4.x * xq0.x + wq4.y * xq1.x + wq4.z * xq2.x + wq4.w * xq3.x;
                accq.y += wq4.x * xq0.y + wq4.y * xq1.y + wq4.z * xq2.y + wq4.w * xq3.y;
                accq.z += wq4.x * xq0.z + wq4.y * xq1.z + wq4.z * xq2.z + wq4.w * xq3.z;
                accq.w += wq4.x * xq0.w + wq4.y * xq1.w + wq4.z * xq2.w + wq4.w * xq3.w;
            }
        }
        float bk = enc_b[C_ + h * HC_ + kvr];
        float bv = enc_b[2 * C_ + h * HC_ + kvr];
        acck.x += bk; acck.y += bk; acck.z += bk; acck.w += bk;
        accv.x += bv; accv.y += bv; accv.z += bv; accv.w += bv;
        *reinterpret_cast<float4*>(&qkv_s[32 + kvr][kvc4]) = acck;
        *reinterpret_cast<float4*>(&qkv_s[64 + kvr][kvc4]) = accv;
        if (t < 256) {
            float bq = enc_b[h * HC_ + qr];
            accq.x += bq; accq.y += bq; accq.z += bq; accq.w += bq;
            *reinterpret_cast<float4*>(&qkv_s[qr][qc4]) = accq;
        }
    }
    __syncthreads();

    // ---- scores: 1 (l, lp-quad) per thread ----
    {
        const int l   = t >> 4;           // local query row 0..31
        const int lp0 = (t & 15) * 4;
        const int qcol = half * 32 + l;
        float4 a4 = {0.f, 0.f, 0.f, 0.f};
        #pragma unroll
        for (int cc = 0; cc < HC_; ++cc) {
            float qv_ = qkv_s[cc][qcol];
            float4 k4 = *reinterpret_cast<const float4*>(&qkv_s[32 + cc][lp0]);
            a4.x += qv_ * k4.x; a4.y += qv_ * k4.y;
            a4.z += qv_ * k4.z; a4.w += qv_ * k4.w;
        }
        a4.x *= SQRT32F; a4.y *= SQRT32F; a4.z *= SQRT32F; a4.w *= SQRT32F;
        *reinterpret_cast<float4*>(&P[l][lp0]) = a4;
    }
    __syncthreads();

    // ---- softmax: 16 threads/row, 4 elems each ----
    {
        int l = t >> 4, p0 = (t & 15) * 4;
        float m = -1e30f;
        #pragma unroll
        for (int j = 0; j < 4; ++j) m = fmaxf(m, P[l][p0 + j]);
        m = fmaxf(m, __shfl_xor(m, 1));
        m = fmaxf(m, __shfl_xor(m, 2));
        m = fmaxf(m, __shfl_xor(m, 4));
        m = fmaxf(m, __shfl_xor(m, 8));
        float sum = 0.f;
        #pragma unroll
        for (int j = 0; j < 4; ++j) {
            float e = __expf(P[l][p0 + j] - m);
            P[l][p0 + j] = e;
            sum += e;
        }
        sum += __shfl_xor(sum, 1);
        sum += __shfl_xor(sum, 2);
        sum += __shfl_xor(sum, 4);
        sum += __shfl_xor(sum, 8);
        float inv = 1.0f / sum;
        #pragma unroll
        for (int j = 0; j < 4; ++j) P[l][p0 + j] *= inv;
    }
    __syncthreads();

    // ---- PV (2 l's x 1 cc per thread) + Fourier recurrence + residual ----
    {
        const int l0 = (t & 15) * 2;      // local l pair
        const int cc = t >> 4;            // 0..31
        float a0 = 0.f, a1 = 0.f;
        #pragma unroll
        for (int sq = 0; sq < 16; ++sq) {
            float4 p0v = *reinterpret_cast<const float4*>(&P[l0 + 0][sq * 4]);
            float4 p1v = *reinterpret_cast<const float4*>(&P[l0 + 1][sq * 4]);
            float4 v4  = *reinterpret_cast<const float4*>(&qkv_s[64 + cc][sq * 4]);
            a0 += p0v.x * v4.x + p0v.y * v4.y + p0v.z * v4.z + p0v.w * v4.w;
            a1 += p1v.x * v4.x + p1v.y * v4.y + p1v.z * v4.z + p1v.w * v4.w;
        }
        const float* wrf = wts[cc];
        const int c  = h * HC_ + cc;
        const int lg = half * 32 + l0;
        float av[2] = {a0, a1};
        float vv[2];
        #pragma unroll
        for (int i = 0; i < 2; ++i) {
            float val = Xs[c][lg + i] + wrf[M_];   // m=0: sin=0, cos=1
            float base = av[i] * (PI_F / (float)M_);
            float s1, c1;
            __sincosf(base, &s1, &c1);
            float sm = 0.f, cm = 1.f;
            #pragma unroll
            for (int m = 1; m < M_; ++m) {
                float sp = sm * c1 + cm * s1;
                float cp = cm * c1 - sm * s1;
                sm = sp; cm = cp;
                val += wrf[m] * sm + wrf[M_ + m] * cm;
            }
            vv[i] = val;
        }
        *reinterpret_cast<float2*>(&enc[((size_t)b * C_ + c) * L_ + lg]) =
            make_float2(vv[0], vv[1]);
    }
}

// ---------------------------------------------------------------------------
// Kernel 2: decoder attention (constant query) per (b,h). 128 blocks x 64.
// qv computed inline (2 threads/row); R7-proven attention body.
// ---------------------------------------------------------------------------
__global__ __launch_bounds__(64) void dec_attn(const float* __restrict__ enc,
                                               const float* __restrict__ dec_w,
                                               const float* __restrict__ dec_b,
                                               const float* __restrict__ mt,
                                               float* __restrict__ xnp_out) {
    __shared__ float qvs[HC_];
    __shared__ float aw[L_];
    const int l = threadIdx.x;           // 0..63
    const int b = blockIdx.x >> 3;
    const int h = blockIdx.x & 7;
    const float* ench = enc + ((size_t)b * C_ + h * HC_) * L_;

    // qv[h*32+r] = dec_w[row] . mt + dec_b   (2 threads per row)
    {
        int r = l >> 1, part = l & 1;
        const float* wr = dec_w + (size_t)(h * HC_ + r) * C_ + part * 128;
        const float* mp = mt + part * 128;
        float s = 0.f;
        #pragma unroll
        for (int j = 0; j < 32; ++j) {
            float4 w4 = *reinterpret_cast<const float4*>(&wr[j * 4]);
            float4 m4 = *reinterpret_cast<const float4*>(&mp[j * 4]);
            s += w4.x * m4.x + w4.y * m4.y + w4.z * m4.z + w4.w * m4.w;
        }
        s += __shfl_xor(s, 1);
        if (part == 0) qvs[r] = s + dec_b[h * HC_ + r];
    }
    __syncthreads();

    float s = 0.f;
    #pragma unroll
    for (int cc = 0; cc < HC_; ++cc)
        s += qvs[cc] * ench[cc * L_ + l];   // coalesced over l
    s *= SQRT32F;
    float m = s;
    #pragma unroll
    for (int off = 32; off >= 1; off >>= 1) m = fmaxf(m, __shfl_xor(m, off));
    float e = __expf(s - m);
    float sum = e;
    #pragma unroll
    for (int off = 32; off >= 1; off >>= 1) sum += __shfl_xor(sum, off);
    aw[l] = e / sum;
    __syncthreads();

    if (l < HC_) {
        const float* vrow = ench + l * L_;
        float a = 0.f;
        #pragma unroll
        for (int k4 = 0; k4 < L_; k4 += 4) {
            float4 a4 = *reinterpret_cast<const float4*>(&aw[k4]);
            float4 v4 = *reinterpret_cast<const float4*>(&vrow[k4]);
            a += a4.x * v4.x + a4.y * v4.y + a4.z * v4.z + a4.w * v4.w;
        }
        int c = h * HC_ + l;
        xnp_out[b * C_ + c] = a + mt[c];
    }
}

// ---------------------------------------------------------------------------
// Kernel 3: fc blocks first, nontemporal streaming stores. (proven R10)
// ---------------------------------------------------------------------------
__global__ __launch_bounds__(256) void bcast_fc(const float* __restrict__ xnp,
                                                const float* __restrict__ fc1_w,
                                                const float* __restrict__ fc1_g,
                                                const float* __restrict__ fc1_b,
                                                const float* __restrict__ fc2_w,
                                                const float* __restrict__ fc2_g,
                                                const float* __restrict__ fc2_b,
                                                float* __restrict__ out) {
    const int t = threadIdx.x;
    const int blk = blockIdx.x;
    if (blk >= 16) {
        int rowid = blk - 16;                 // (b,c) row
        float v = xnp[rowid];
        v4f V = {v, v, v, v};
        v4f* row = reinterpret_cast<v4f*>(out + (size_t)rowid * N_);
        #pragma unroll
        for (int i = 0; i < 8; ++i)
            __builtin_nontemporal_store(V, &row[t + i * 256]);   // 2048 x 16B
    } else {
        int b = blk;
        __shared__ float xs[C_];
        __shared__ float y1[C_];
        __shared__ float y2s[4];
        xs[t] = xnp[b * C_ + t];
        __syncthreads();
        {
            const float* wrow = fc1_w + (size_t)t * C_;
            float s = 0.f;
            #pragma unroll 8
            for (int c4 = 0; c4 < C_; c4 += 4) {
                float4 w4 = *reinterpret_cast<const float4*>(&wrow[c4]);
                float4 x4 = *reinterpret_cast<const float4*>(&xs[c4]);
                s += w4.x * x4.x + w4.y * x4.y + w4.z * x4.z + w4.w * x4.w;
            }
            float y = fc1_g[t] * s * BN_INV + fc1_b[t];
            y1[t] = (y >= 0.f) ? y : 0.2f * y;
        }
        __syncthreads();
        if (t < 3) {
            const float* wrow = fc2_w + t * C_;
            float s = 0.f;
            #pragma unroll 8
            for (int c4 = 0; c4 < C_; c4 += 4) {
                float4 w4 = *reinterpret_cast<const float4*>(&wrow[c4]);
                float4 x4 = *reinterpret_cast<const float4*>(&y1[c4]);
                s += w4.x * x4.x + w4.y * x4.y + w4.z * x4.z + w4.w * x4.w;
            }
            float y = fc2_g[t] * s * BN_INV + fc2_b[t];
            y2s[t] = (y >= 0.f) ? y : 0.2f * y;
        }
        __syncthreads();
        float v0 = y2s[0], v1 = y2s[1], v2 = y2s[2];
        v4f pat0 = {v0, v1, v2, v0};
        v4f pat1 = {v1, v2, v0, v1};
        v4f pat2 = {v2, v0, v1, v2};
        int r = t % 3;
        v4f a = (r == 0) ? pat0 : (r == 1) ? pat1 : pat2;
        v4f bb = (r == 0) ? pat1 : (r == 1) ? pat2 : pat0;
        v4f c = (r == 0) ? pat2 : (r == 1) ? pat0 : pat1;
        v4f* o1 = reinterpret_cast<v4f*>(
            out + (size_t)B_ * C_ * N_ + (size_t)b * (N_ * 3));
        #pragma unroll
        for (int i = 0; i < 24; i += 3) {    // 6144 float4 = 8192*3 f32
            __builtin_nontemporal_store(a,  &o1[t + (i + 0) * 256]);
            __builtin_nontemporal_store(bb, &o1[t + (i + 1) * 256]);
            __builtin_nontemporal_store(c,  &o1[t + (i + 2) * 256]);
        }
    }
}

// ---------------------------------------------------------------------------
extern "C" void kernel_launch(void* const* d_in, const int* in_sizes, int n_in,
                              void* d_out, int out_size, void* d_ws, size_t ws_size,
                              hipStream_t stream) {
    const float* xt      = (const float*)d_in[0];
    // d_in[1] = xn : unused (length N is compile-time)
    const float* weights = (const float*)d_in[2];
    const float* mt      = (const float*)d_in[3];
    const float* enc_w   = (const float*)d_in[4];
    const float* enc_b   = (const float*)d_in[5];
    const float* dec_w   = (const float*)d_in[6];
    const float* dec_b   = (const float*)d_in[7];
    const float* fc1_w   = (const float*)d_in[8];
    const float* fc1_g   = (const float*)d_in[9];
    const float* fc1_b   = (const float*)d_in[10];
    const float* fc2_w   = (const float*)d_in[11];
    const float* fc2_g   = (const float*)d_in[12];
    const float* fc2_b   = (const float*)d_in[13];

    float* ws  = (float*)d_ws;
    float* enc = ws;                  // 262144 floats (1 MB)
    float* xnp = ws + 262144;         // 4096 floats

    float* out = (float*)d_out;

    enc_half<<<256, 512, 0, stream>>>(xt, enc_w, enc_b, weights, enc);
    dec_attn<<<128, 64, 0, stream>>>(enc, dec_w, dec_b, mt, xnp);
    bcast_fc<<<4112, 256, 0, stream>>>(xnp, fc1_w, fc1_g, fc1_b,
                                       fc2_w, fc2_g, fc2_b, out);
}